// Round 6
// baseline (697.872 us; speedup 1.0000x reference)
//
#include <hip/hip_runtime.h>
#include <hip/hip_bf16.h>
#include <stdint.h>

// Problem constants
#define N_PATCH 3136     // 56*56 query rows
#define N_PATCH_PAD 3200 // 25 m-tiles * 128
#define N_LIB   16384    // memory bank rows
#define DIM     768
#define IMGSZ   224
#define FM      56

// GEMM tiling
#define BK 32
#define KT 24            // DIM/BK
#define MT 25            // m-tiles
#define NTILES 128       // n-tiles (16384/128)

typedef __bf16 bf16_t;
typedef __bf16 bf16x8 __attribute__((ext_vector_type(8)));
typedef __bf16 bf16x4_v __attribute__((ext_vector_type(4)));
typedef float  f32x4  __attribute__((ext_vector_type(4)));

#define FLT_MAX_ 3.402823466e+38f

struct Scal {
  unsigned long long approx_max_pack;   // (bits(sqrt-min)<<32) | (0xffffffff - row)
  unsigned long long cand_pack[64];     // per-candidate exact (bits(d2)<<32)|argmin_j
  int cand[64];
  int cand_count;
  int done1;                            // finalize block counter
  int done2;                            // wdist block counter
};

__device__ __forceinline__ float wave_reduce_sum(float v) {
#pragma unroll
  for (int s = 32; s > 0; s >>= 1) v += __shfl_xor(v, s, 64);
  return v;
}

__device__ __forceinline__ unsigned long long shfl_xor_u64(unsigned long long v, int mask) {
  unsigned lo = (unsigned)v, hi = (unsigned)(v >> 32);
  lo = __shfl_xor(lo, mask, 64);
  hi = __shfl_xor(hi, mask, 64);
  return ((unsigned long long)hi << 32) | lo;
}

// async global->LDS, 16B per lane; LDS dest = wave-uniform base + lane*size
__device__ __forceinline__ void async16(const bf16_t* g, bf16_t* l) {
  __builtin_amdgcn_global_load_lds(
      (const __attribute__((address_space(1))) unsigned int*)g,
      (__attribute__((address_space(3))) unsigned int*)l, 16, 0, 0);
}

// ------------------------------------------------- prep: normalize + bf16 + norms
// blocks [0,784): patch rows (wave per row); blocks [784, 784+4096): lib rows
__global__ void prep_kernel(const float* __restrict__ patch, const float* __restrict__ lib,
                            const float* __restrict__ meanp, const float* __restrict__ stdp,
                            bf16_t* __restrict__ pb, bf16_t* __restrict__ lb,
                            float* __restrict__ a2, float* __restrict__ b2, Scal* sc) {
  int t = threadIdx.x;
  int lane = t & 63;
  if (blockIdx.x == 0) {  // init (runs before any consumer kernel: stream order)
    if (t < 64) sc->cand_pack[t] = ~0ULL;
    if (t == 64) { sc->approx_max_pack = 0ULL; sc->cand_count = 0; sc->done1 = 0; sc->done2 = 0; }
  }
  if (blockIdx.x < N_PATCH / 4) {
    int row = blockIdx.x * 4 + (t >> 6);
    float mu = meanp[0], sd = stdp[0];
    float acc = 0.f;
#pragma unroll
    for (int k = 0; k < 3; k++) {
      float4 v = ((const float4*)(patch + (size_t)row * DIM))[lane + 64 * k];
      v.x = (v.x - mu) / sd; v.y = (v.y - mu) / sd;
      v.z = (v.z - mu) / sd; v.w = (v.w - mu) / sd;
      bf16x4_v o = {(__bf16)v.x, (__bf16)v.y, (__bf16)v.z, (__bf16)v.w};
      *(bf16x4_v*)(pb + (size_t)row * DIM + (lane + 64 * k) * 4) = o;
      acc += v.x*v.x + v.y*v.y + v.z*v.z + v.w*v.w;
    }
    acc = wave_reduce_sum(acc);
    if (lane == 0) a2[row] = acc;
  } else {
    int row = (blockIdx.x - N_PATCH / 4) * 4 + (t >> 6);
    float acc = 0.f;
#pragma unroll
    for (int k = 0; k < 3; k++) {
      float4 v = ((const float4*)(lib + (size_t)row * DIM))[lane + 64 * k];
      bf16x4_v o = {(__bf16)v.x, (__bf16)v.y, (__bf16)v.z, (__bf16)v.w};
      *(bf16x4_v*)(lb + (size_t)row * DIM + (lane + 64 * k) * 4) = o;
      acc += v.x*v.x + v.y*v.y + v.z*v.z + v.w*v.w;
    }
    acc = wave_reduce_sum(acc);
    if (lane == 0) b2[row] = acc;
  }
}

// ------------------------------------------------- fused bf16 GEMM + row-min
// 3200 blocks (XCD-swizzled), 256 threads = 4 waves; block tile 128(M) x 128(N),
// global_load_lds width-16 staging, LDS double buffer, one barrier per K-step.
// Epilogue: float-only row min -> part[ntile][row] (coalesced).
__global__ __launch_bounds__(256, 4)
void gemm_min_kernel(const bf16_t* __restrict__ pb, const bf16_t* __restrict__ lb,
                     const float* __restrict__ a2, const float* __restrict__ b2,
                     float* __restrict__ part) {
  __shared__ __align__(16) bf16_t As[2][128 * BK];
  __shared__ __align__(16) bf16_t Bs[2][128 * BK];
  __shared__ unsigned smin[128];

  const int t = threadIdx.x;
  const int wave = t >> 6;
  const int lane = t & 63;
  const int l15 = lane & 15;
  const int quad = lane >> 4;
  const int wm = (wave >> 1) * 64;
  const int wn = (wave & 1) * 64;

  // XCD swizzle: one XCD owns 16 consecutive-mod-8 ntiles -> lb slice ~3MB L2-resident
  const int lid = blockIdx.x;
  const int xcd = lid & 7;
  const int slot = lid >> 3;               // 0..399
  const int ntile = xcd + 8 * (slot / MT); // 0..127
  const int mtile = slot % MT;
  const int m0 = mtile * 128;
  const int n0 = ntile * 128;

  int ra0 = m0 + (t >> 2);       if (ra0 > N_PATCH - 1) ra0 = N_PATCH - 1;
  int ra1 = m0 + 64 + (t >> 2);  if (ra1 > N_PATCH - 1) ra1 = N_PATCH - 1;
  const bf16_t* gA0 = pb + (size_t)ra0 * DIM + (t & 3) * 8;
  const bf16_t* gA1 = pb + (size_t)ra1 * DIM + (t & 3) * 8;
  const bf16_t* gB0 = lb + (size_t)(n0 + (t >> 2)) * DIM + (t & 3) * 8;
  const bf16_t* gB1 = gB0 + (size_t)64 * DIM;

  if (t < 128) smin[t] = 0xffffffffu;

  {
    bf16_t* la = &As[0][0];
    bf16_t* lb_ = &Bs[0][0];
    async16(gA0, la + t * 8);
    async16(gA1, la + 2048 + t * 8);
    async16(gB0, lb_ + t * 8);
    async16(gB1, lb_ + 2048 + t * 8);
  }
  __syncthreads();

  f32x4 acc[4][4];
#pragma unroll
  for (int mi = 0; mi < 4; mi++)
#pragma unroll
    for (int ni = 0; ni < 4; ni++) { f32x4 z = {0.f,0.f,0.f,0.f}; acc[mi][ni] = z; }

  for (int k = 0; k < KT; ++k) {
    const int cur = k & 1;
    if (k + 1 < KT) {
      const int nxt = cur ^ 1;
      const size_t ko = (size_t)(k + 1) * BK;
      bf16_t* la = &As[nxt][0];
      bf16_t* lb_ = &Bs[nxt][0];
      async16(gA0 + ko, la + t * 8);
      async16(gA1 + ko, la + 2048 + t * 8);
      async16(gB0 + ko, lb_ + t * 8);
      async16(gB1 + ko, lb_ + 2048 + t * 8);
    }

    bf16x8 afr[4], bfr[4];
#pragma unroll
    for (int mi = 0; mi < 4; mi++)
      afr[mi] = *(const bf16x8*)(&As[cur][(wm + mi * 16 + l15) * BK + quad * 8]);
#pragma unroll
    for (int ni = 0; ni < 4; ni++)
      bfr[ni] = *(const bf16x8*)(&Bs[cur][(wn + ni * 16 + l15) * BK + quad * 8]);
#pragma unroll
    for (int mi = 0; mi < 4; mi++)
#pragma unroll
      for (int ni = 0; ni < 4; ni++)
        acc[mi][ni] = __builtin_amdgcn_mfma_f32_16x16x32_bf16(afr[mi], bfr[ni],
                                                              acc[mi][ni], 0, 0, 0);
    __syncthreads();
  }

  // epilogue: d2 = a2 + b2 - 2*dot; float-only min (no index)
  float b2n[4];
#pragma unroll
  for (int ni = 0; ni < 4; ni++) b2n[ni] = b2[n0 + wn + ni * 16 + l15];

#pragma unroll
  for (int mi = 0; mi < 4; mi++) {
#pragma unroll
    for (int r = 0; r < 4; r++) {
      int rloc = wm + mi * 16 + quad * 4 + r;
      int mrow = m0 + rloc;
      float a2v = a2[mrow < N_PATCH ? mrow : (N_PATCH - 1)];
      // C/D layout: col = lane&15, row = quad*4 + reg  [m89/m91]
      float best = a2v + b2n[0] - 2.0f * acc[mi][0][r];
#pragma unroll
      for (int ni = 1; ni < 4; ni++)
        best = fminf(best, a2v + b2n[ni] - 2.0f * acc[mi][ni][r]);
      best = fmaxf(best, 0.0f);
#pragma unroll
      for (int s = 1; s < 16; s <<= 1)
        best = fminf(best, __shfl_xor(best, s, 64));
      if (l15 == 0) atomicMin(&smin[rloc], __float_as_uint(best));
    }
  }
  __syncthreads();
  if (t < 128) part[(size_t)ntile * N_PATCH_PAD + m0 + t] = __uint_as_float(smin[t]);
}

// ------------------------------------------------- finalize + collect (last-block fused)
// 25 blocks x 128 threads; thread t owns row b*128+t; coalesced column reads.
__global__ void finalize_collect_kernel(const float* __restrict__ part,
                                        float* __restrict__ min_val, Scal* sc) {
  __shared__ bool last;
  int t = threadIdx.x;
  int row = blockIdx.x * 128 + t;
  float m = FLT_MAX_;
#pragma unroll 8
  for (int nt = 0; nt < NTILES; nt++)
    m = fminf(m, part[(size_t)nt * N_PATCH_PAD + row]);
  if (row < N_PATCH) {
    float v = sqrtf(m);
    min_val[row] = v;
    unsigned long long mp = (((unsigned long long)__float_as_uint(v)) << 32) |
                            (unsigned)(0xffffffffu - (unsigned)row);  // ties -> smaller row
    atomicMax(&sc->approx_max_pack, mp);
  }
  __threadfence();
  __syncthreads();
  if (t == 0) last = (atomicAdd(&sc->done1, 1) == MT - 1);
  __syncthreads();
  if (!last) return;
  __threadfence();
  float amax = __uint_as_float((unsigned)(atomicMax(&sc->approx_max_pack, 0ULL) >> 32));
  for (int i = t; i < N_PATCH; i += 128) {
    if (min_val[i] >= amax - 0.02f) {   // >6 sigma of bf16 noise
      int p = atomicAdd(&sc->cand_count, 1);
      if (p < 64) sc->cand[p] = i;
    }
  }
}

// ------------------------------------------------- exact fp32 refine of candidates
// grid (64 candidates, 128 chunks of 128 rows), block 256 = 4 waves x 32 rows
__global__ void refine_kernel(const float* __restrict__ patch, const float* __restrict__ lib,
                              const float* __restrict__ meanp, const float* __restrict__ stdp,
                              Scal* sc) {
  int c = blockIdx.x;
  int cnt = sc->cand_count; if (cnt > 64) cnt = 64;
  if (c >= cnt) return;
  int row = sc->cand[c];
  int wave = threadIdx.x >> 6, lane = threadIdx.x & 63;
  float mu = meanp[0], sd = stdp[0];
  float4 pv[3];
#pragma unroll
  for (int k = 0; k < 3; k++) {
    float4 v = ((const float4*)(patch + (size_t)row * DIM))[lane + 64 * k];
    v.x = (v.x - mu) / sd; v.y = (v.y - mu) / sd;
    v.z = (v.z - mu) / sd; v.w = (v.w - mu) / sd;
    pv[k] = v;
  }
  unsigned long long best = ~0ULL;
  int jbase = blockIdx.y * 128 + wave * 32;
  for (int rr = 0; rr < 32; rr++) {
    int j = jbase + rr;
    const float4* pl = (const float4*)(lib + (size_t)j * DIM);
    float acc = 0.f;
#pragma unroll
    for (int k = 0; k < 3; k++) {
      float4 l = pl[lane + 64 * k];
      float dx = pv[k].x - l.x, dy = pv[k].y - l.y;
      float dz = pv[k].z - l.z, dw = pv[k].w - l.w;
      acc += dx*dx + dy*dy + dz*dz + dw*dw;
    }
    acc = wave_reduce_sum(acc);
    unsigned long long pk = (((unsigned long long)__float_as_uint(acc)) << 32) | (unsigned)j;
    if (pk < best) best = pk;
  }
  if (lane == 0) atomicMin(&sc->cand_pack[c], best);
}

// inline "pick": wave-level max over candidates
__device__ __forceinline__ void wave_pick(const Scal* sc, int lane,
                                          int* srow, float* sstar, int* ms) {
  int cnt = sc->cand_count; if (cnt > 64) cnt = 64;
  unsigned long long pk = 0ULL;
  int rowv = 0, msv = 0;
  if (lane < cnt) {
    unsigned long long cp = sc->cand_pack[lane];
    rowv = sc->cand[lane];
    msv = (int)(cp & 0xffffffffu);
    pk = (cp & 0xffffffff00000000ULL) | (unsigned)(0xffffffffu - (unsigned)rowv);
  }
  unsigned long long m = pk;
#pragma unroll
  for (int s = 1; s < 64; s <<= 1) {
    unsigned long long o = shfl_xor_u64(m, s);
    if (o > m) m = o;
  }
  unsigned long long mask = __ballot(pk == m && lane < cnt);
  int wl = (int)(__ffsll((long long)mask) - 1);
  *srow = __shfl(rowv, wl, 64);
  *ms   = __shfl(msv, wl, 64);
  *sstar = sqrtf(__uint_as_float((unsigned)(m >> 32)));
}

// ------------------------------------------------- w_dist + top3 + scalar (last-block fused)
// 4096 blocks x 256 threads, wave per lib row (4/block); last block merges top-3
// (packed u64: unique keys, tie -> smaller j, matching lax.top_k) and computes s.
__global__ void wdist_top3_kernel(const float* __restrict__ lib,
                                  const float* __restrict__ patch,
                                  const float* __restrict__ meanp,
                                  const float* __restrict__ stdp,
                                  Scal* sc, float* __restrict__ wdist2,
                                  float* __restrict__ out) {
  __shared__ unsigned long long sl[768];
  __shared__ int sms;
  __shared__ bool last;
  int t = threadIdx.x;
  int wave = t >> 6, lane = t & 63;

  if (wave == 0) {
    int srow_, ms_; float ss_;
    wave_pick(sc, lane, &srow_, &ss_, &ms_);
    if (lane == 0) sms = ms_;
  }
  __syncthreads();
  int ms = sms;
  int j = blockIdx.x * 4 + wave;
  {
    const float4* pj = (const float4*)(lib + (size_t)j * DIM);
    const float4* pm = (const float4*)(lib + (size_t)ms * DIM);
    float acc = 0.f;
#pragma unroll
    for (int k = 0; k < 3; k++) {
      float4 a = pj[lane + 64 * k], b = pm[lane + 64 * k];
      float dx = a.x - b.x, dy = a.y - b.y, dz = a.z - b.z, dw = a.w - b.w;
      acc += dx*dx + dy*dy + dz*dz + dw*dw;
    }
    acc = wave_reduce_sum(acc);
    if (lane == 0) wdist2[j] = acc;
  }
  __threadfence();
  __syncthreads();
  if (t == 0) last = (atomicAdd(&sc->done2, 1) == N_LIB / 4 - 1);
  __syncthreads();
  if (!last) return;
  __threadfence();

  // ---- top3 merge over all 16384 wdist2 ----
  unsigned long long b0 = ~0ULL, b1 = ~0ULL, b2 = ~0ULL;
  for (int jj = t; jj < N_LIB; jj += 256) {
    unsigned long long pk = (((unsigned long long)__float_as_uint(wdist2[jj])) << 32) | (unsigned)jj;
    if (pk < b0)      { b2 = b1; b1 = b0; b0 = pk; }
    else if (pk < b1) { b2 = b1; b1 = pk; }
    else if (pk < b2) { b2 = pk; }
  }
  sl[t * 3 + 0] = b0; sl[t * 3 + 1] = b1; sl[t * 3 + 2] = b2;
  __syncthreads();
  if (t >= 64) return;

  unsigned long long c0 = ~0ULL, c1 = ~0ULL, c2 = ~0ULL;
#pragma unroll
  for (int e = 0; e < 12; e++) {
    unsigned long long pk = sl[t * 12 + e];
    if (pk < c0)      { c2 = c1; c1 = c0; c0 = pk; }
    else if (pk < c1) { c2 = c1; c1 = pk; }
    else if (pk < c2) { c2 = pk; }
  }
  unsigned long long res1 = 0, res2 = 0;
#pragma unroll
  for (int r = 0; r < 3; r++) {
    unsigned long long m = c0;
#pragma unroll
    for (int s = 1; s < 64; s <<= 1) {
      unsigned long long o = shfl_xor_u64(m, s);
      if (o < m) m = o;
    }
    if (r == 1) res1 = m;
    if (r == 2) res2 = m;
    if (c0 == m) { c0 = c1; c1 = c2; c2 = ~0ULL; }
  }
  int nA = (int)(res1 & 0xffffffffu);   // 2nd nearest
  int nB = (int)(res2 & 0xffffffffu);   // 3rd nearest

  int srow, ms2; float sstar;
  wave_pick(sc, t, &srow, &sstar, &ms2);

  float mu = meanp[0], sd = stdp[0];
  float accA = 0.f, accB = 0.f;
#pragma unroll
  for (int k = 0; k < 3; k++) {
    float4 p4 = ((const float4*)(patch + (size_t)srow * DIM))[t + 64 * k];
    float4 a4 = ((const float4*)(lib + (size_t)nA * DIM))[t + 64 * k];
    float4 b4 = ((const float4*)(lib + (size_t)nB * DIM))[t + 64 * k];
    float px = (p4.x - mu) / sd, py = (p4.y - mu) / sd;
    float pz = (p4.z - mu) / sd, pw = (p4.w - mu) / sd;
    float dax = px - a4.x, day = py - a4.y, daz = pz - a4.z, daw = pw - a4.w;
    float dbx = px - b4.x, dby = py - b4.y, dbz = pz - b4.z, dbw = pw - b4.w;
    accA += dax*dax + day*day + daz*daz + daw*daw;
    accB += dbx*dbx + dby*dby + dbz*dbz + dbw*dbw;
  }
  accA = wave_reduce_sum(accA);
  accB = wave_reduce_sum(accB);
  if (t == 0) {
    float dsq = sqrtf((float)DIM);
    float d1 = sqrtf(accA), d2v = sqrtf(accB);
    float w = 1.0f - expf(sstar / dsq) / (expf(d1 / dsq) + expf(d2v / dsq));
    out[0] = w * sstar;
  }
}

// ------------------------------------------------- fused bilinear 56->224 + 9x9 blur
// 49 blocks, 256 threads; block = 32x32 output tile; 40x40 resized halo in LDS.
// NOTE: `out` already points at d_out+1 (map base) — do NOT add another +1.
__global__ void resize_blur_kernel(const float* __restrict__ mv, float* __restrict__ out) {
  __shared__ float rs[40 * 40];
  int bx = blockIdx.x % 7, by = blockIdx.x / 7;
  int ox0 = bx * 32, oy0 = by * 32;
  int t = threadIdx.x;

  for (int i = t; i < 1600; i += 256) {
    int ly = i / 40, lx = i % 40;
    int gy = oy0 - 4 + ly; gy = gy < 0 ? 0 : (gy > 223 ? 223 : gy);
    int gx = ox0 - 4 + lx; gx = gx < 0 ? 0 : (gx > 223 ? 223 : gx);
    float sy = fminf(fmaxf(0.25f * gy - 0.375f, 0.0f), 55.0f);
    float sx = fminf(fmaxf(0.25f * gx - 0.375f, 0.0f), 55.0f);
    int y0 = (int)sy; if (y0 > 54) y0 = 54;
    int x0 = (int)sx; if (x0 > 54) x0 = 54;
    float fy = sy - y0, fx = sx - x0;
    float v00 = mv[y0*FM + x0],     v01 = mv[y0*FM + x0 + 1];
    float v10 = mv[(y0+1)*FM + x0], v11 = mv[(y0+1)*FM + x0 + 1];
    float a = v00 + fx * (v01 - v00);
    float b = v10 + fx * (v11 - v10);
    rs[i] = a + fy * (b - a);
  }
  __syncthreads();

  float g[9]; float gs = 0.f;
#pragma unroll
  for (int i = 0; i < 9; i++) { float tt = (float)(i - 4); g[i] = expf(-(tt*tt)/32.0f); gs += g[i]; }
#pragma unroll
  for (int i = 0; i < 9; i++) g[i] /= gs;

  for (int p = t; p < 1024; p += 256) {
    int y = oy0 + p / 32, x = ox0 + (p & 31);
    float acc = 0.f;
#pragma unroll
    for (int dy = 0; dy < 9; dy++) {
      int yy = y + dy - 4;
      yy = yy < 0 ? -yy : (yy > IMGSZ - 1 ? 2*(IMGSZ-1) - yy : yy);
      int lyy = yy - (oy0 - 4);
      float ra = 0.f;
#pragma unroll
      for (int dx = 0; dx < 9; dx++) {
        int xx = x + dx - 4;
        xx = xx < 0 ? -xx : (xx > IMGSZ - 1 ? 2*(IMGSZ-1) - xx : xx);
        ra += g[dx] * rs[lyy * 40 + (xx - (ox0 - 4))];
      }
      acc += g[dy] * ra;
    }
    out[y * IMGSZ + x] = acc;   // FIXED: host passes d_out+1 already
  }
}

// ================================================= host
extern "C" void kernel_launch(void* const* d_in, const int* in_sizes, int n_in,
                              void* d_out, int out_size, void* d_ws, size_t ws_size,
                              hipStream_t stream) {
  const float* patch = (const float*)d_in[0];
  const float* lib   = (const float*)d_in[1];
  const float* meanp = (const float*)d_in[2];
  const float* stdp  = (const float*)d_in[3];
  float* out = (float*)d_out;

  char* ws = (char*)d_ws;
  size_t off = 0;
  auto alloc = [&](size_t bytes) -> void* {
    void* p = ws + off;
    off = (off + bytes + 255) & ~(size_t)255;
    return p;
  };
  bf16_t* pb      = (bf16_t*)alloc((size_t)N_PATCH * DIM * sizeof(bf16_t));
  bf16_t* lb      = (bf16_t*)alloc((size_t)N_LIB * DIM * sizeof(bf16_t));
  float* a2       = (float*)alloc(N_PATCH * sizeof(float));
  float* b2       = (float*)alloc(N_LIB * sizeof(float));
  float* part     = (float*)alloc((size_t)N_PATCH_PAD * NTILES * sizeof(float));
  float* min_val  = (float*)alloc(N_PATCH * sizeof(float));
  float* wdist2   = (float*)alloc(N_LIB * sizeof(float));
  Scal*  sc       = (Scal*)alloc(sizeof(Scal));

  prep_kernel<<<N_PATCH / 4 + N_LIB / 4, 256, 0, stream>>>(patch, lib, meanp, stdp,
                                                           pb, lb, a2, b2, sc);
  gemm_min_kernel<<<MT * NTILES, 256, 0, stream>>>(pb, lb, a2, b2, part);
  finalize_collect_kernel<<<MT, 128, 0, stream>>>(part, min_val, sc);
  refine_kernel<<<dim3(64, 128), 256, 0, stream>>>(patch, lib, meanp, stdp, sc);
  wdist_top3_kernel<<<N_LIB / 4, 256, 0, stream>>>(lib, patch, meanp, stdp, sc, wdist2, out);
  resize_blur_kernel<<<49, 256, 0, stream>>>(min_val, out + 1);
}

// Round 7
// 367.500 us; speedup vs baseline: 1.8990x; 1.8990x over previous
//
#include <hip/hip_runtime.h>
#include <hip/hip_bf16.h>
#include <stdint.h>

// Problem constants
#define N_PATCH 3136     // 56*56 query rows
#define N_PATCH_PAD 3200 // 25 m-tiles * 128
#define N_LIB   16384    // memory bank rows
#define DIM     768
#define IMGSZ   224
#define FM      56

// GEMM tiling
#define BK 32
#define KT 24            // DIM/BK
#define MT 25            // m-tiles
#define NTILES 128       // n-tiles (16384/128)

typedef __bf16 bf16_t;
typedef __bf16 bf16x8 __attribute__((ext_vector_type(8)));
typedef __bf16 bf16x4_v __attribute__((ext_vector_type(4)));
typedef float  f32x4  __attribute__((ext_vector_type(4)));

#define FLT_MAX_ 3.402823466e+38f

struct Scal {
  unsigned long long approx_max_pack;   // (bits(sqrt-min)<<32) | (0xffffffff - row)
  unsigned long long cand_pack[64];     // per-candidate exact (bits(d2)<<32)|argmin_j
  int cand[64];
  int cand_count;
  int done1;                            // finalize block counter
};

__device__ __forceinline__ float wave_reduce_sum(float v) {
#pragma unroll
  for (int s = 32; s > 0; s >>= 1) v += __shfl_xor(v, s, 64);
  return v;
}

__device__ __forceinline__ unsigned long long shfl_xor_u64(unsigned long long v, int mask) {
  unsigned lo = (unsigned)v, hi = (unsigned)(v >> 32);
  lo = __shfl_xor(lo, mask, 64);
  hi = __shfl_xor(hi, mask, 64);
  return ((unsigned long long)hi << 32) | lo;
}

// async global->LDS, 16B per lane; LDS dest = wave-uniform base + lane*size
__device__ __forceinline__ void async16(const bf16_t* g, bf16_t* l) {
  __builtin_amdgcn_global_load_lds(
      (const __attribute__((address_space(1))) unsigned int*)g,
      (__attribute__((address_space(3))) unsigned int*)l, 16, 0, 0);
}

// ------------------------------------------------- prep: normalize + bf16 + norms
// blocks [0,784): patch rows (wave per row); blocks [784, 784+4096): lib rows
__global__ void prep_kernel(const float* __restrict__ patch, const float* __restrict__ lib,
                            const float* __restrict__ meanp, const float* __restrict__ stdp,
                            bf16_t* __restrict__ pb, bf16_t* __restrict__ lb,
                            float* __restrict__ a2, float* __restrict__ b2, Scal* sc) {
  int t = threadIdx.x;
  int lane = t & 63;
  if (blockIdx.x == 0) {  // init (runs before any consumer kernel: stream order)
    if (t < 64) sc->cand_pack[t] = ~0ULL;
    if (t == 64) { sc->approx_max_pack = 0ULL; sc->cand_count = 0; sc->done1 = 0; }
  }
  if (blockIdx.x < N_PATCH / 4) {
    int row = blockIdx.x * 4 + (t >> 6);
    float mu = meanp[0], sd = stdp[0];
    float acc = 0.f;
#pragma unroll
    for (int k = 0; k < 3; k++) {
      float4 v = ((const float4*)(patch + (size_t)row * DIM))[lane + 64 * k];
      v.x = (v.x - mu) / sd; v.y = (v.y - mu) / sd;
      v.z = (v.z - mu) / sd; v.w = (v.w - mu) / sd;
      bf16x4_v o = {(__bf16)v.x, (__bf16)v.y, (__bf16)v.z, (__bf16)v.w};
      *(bf16x4_v*)(pb + (size_t)row * DIM + (lane + 64 * k) * 4) = o;
      acc += v.x*v.x + v.y*v.y + v.z*v.z + v.w*v.w;
    }
    acc = wave_reduce_sum(acc);
    if (lane == 0) a2[row] = acc;
  } else {
    int row = (blockIdx.x - N_PATCH / 4) * 4 + (t >> 6);
    float acc = 0.f;
#pragma unroll
    for (int k = 0; k < 3; k++) {
      float4 v = ((const float4*)(lib + (size_t)row * DIM))[lane + 64 * k];
      bf16x4_v o = {(__bf16)v.x, (__bf16)v.y, (__bf16)v.z, (__bf16)v.w};
      *(bf16x4_v*)(lb + (size_t)row * DIM + (lane + 64 * k) * 4) = o;
      acc += v.x*v.x + v.y*v.y + v.z*v.z + v.w*v.w;
    }
    acc = wave_reduce_sum(acc);
    if (lane == 0) b2[row] = acc;
  }
}

// ------------------------------------------------- fused bf16 GEMM + row-min
// 3200 blocks (XCD-swizzled), 256 threads = 4 waves; block tile 128(M) x 128(N),
// global_load_lds width-16 staging, LDS double buffer, one barrier per K-step.
// Epilogue: float-only row min -> part[ntile][row] (coalesced).
__global__ __launch_bounds__(256, 3)
void gemm_min_kernel(const bf16_t* __restrict__ pb, const bf16_t* __restrict__ lb,
                     const float* __restrict__ a2, const float* __restrict__ b2,
                     float* __restrict__ part) {
  __shared__ __align__(16) bf16_t As[2][128 * BK];
  __shared__ __align__(16) bf16_t Bs[2][128 * BK];
  __shared__ unsigned smin[128];

  const int t = threadIdx.x;
  const int wave = t >> 6;
  const int lane = t & 63;
  const int l15 = lane & 15;
  const int quad = lane >> 4;
  const int wm = (wave >> 1) * 64;
  const int wn = (wave & 1) * 64;

  // XCD swizzle: one XCD owns 16 consecutive-mod-8 ntiles -> lb slice ~3MB L2-resident
  const int lid = blockIdx.x;
  const int xcd = lid & 7;
  const int slot = lid >> 3;               // 0..399
  const int ntile = xcd + 8 * (slot / MT); // 0..127
  const int mtile = slot % MT;
  const int m0 = mtile * 128;
  const int n0 = ntile * 128;

  int ra0 = m0 + (t >> 2);       if (ra0 > N_PATCH - 1) ra0 = N_PATCH - 1;
  int ra1 = m0 + 64 + (t >> 2);  if (ra1 > N_PATCH - 1) ra1 = N_PATCH - 1;
  const bf16_t* gA0 = pb + (size_t)ra0 * DIM + (t & 3) * 8;
  const bf16_t* gA1 = pb + (size_t)ra1 * DIM + (t & 3) * 8;
  const bf16_t* gB0 = lb + (size_t)(n0 + (t >> 2)) * DIM + (t & 3) * 8;
  const bf16_t* gB1 = gB0 + (size_t)64 * DIM;

  if (t < 128) smin[t] = 0xffffffffu;

  {
    bf16_t* la = &As[0][0];
    bf16_t* lb_ = &Bs[0][0];
    async16(gA0, la + t * 8);
    async16(gA1, la + 2048 + t * 8);
    async16(gB0, lb_ + t * 8);
    async16(gB1, lb_ + 2048 + t * 8);
  }
  __syncthreads();

  f32x4 acc[4][4];
#pragma unroll
  for (int mi = 0; mi < 4; mi++)
#pragma unroll
    for (int ni = 0; ni < 4; ni++) { f32x4 z = {0.f,0.f,0.f,0.f}; acc[mi][ni] = z; }

  for (int k = 0; k < KT; ++k) {
    const int cur = k & 1;
    if (k + 1 < KT) {
      const int nxt = cur ^ 1;
      const size_t ko = (size_t)(k + 1) * BK;
      bf16_t* la = &As[nxt][0];
      bf16_t* lb_ = &Bs[nxt][0];
      async16(gA0 + ko, la + t * 8);
      async16(gA1 + ko, la + 2048 + t * 8);
      async16(gB0 + ko, lb_ + t * 8);
      async16(gB1 + ko, lb_ + 2048 + t * 8);
    }

    bf16x8 afr[4], bfr[4];
#pragma unroll
    for (int mi = 0; mi < 4; mi++)
      afr[mi] = *(const bf16x8*)(&As[cur][(wm + mi * 16 + l15) * BK + quad * 8]);
#pragma unroll
    for (int ni = 0; ni < 4; ni++)
      bfr[ni] = *(const bf16x8*)(&Bs[cur][(wn + ni * 16 + l15) * BK + quad * 8]);
#pragma unroll
    for (int mi = 0; mi < 4; mi++)
#pragma unroll
      for (int ni = 0; ni < 4; ni++)
        acc[mi][ni] = __builtin_amdgcn_mfma_f32_16x16x32_bf16(afr[mi], bfr[ni],
                                                              acc[mi][ni], 0, 0, 0);
    __syncthreads();
  }

  // epilogue: d2 = a2 + b2 - 2*dot; float-only min (no index)
  float b2n[4];
#pragma unroll
  for (int ni = 0; ni < 4; ni++) b2n[ni] = b2[n0 + wn + ni * 16 + l15];

#pragma unroll
  for (int mi = 0; mi < 4; mi++) {
#pragma unroll
    for (int r = 0; r < 4; r++) {
      int rloc = wm + mi * 16 + quad * 4 + r;
      int mrow = m0 + rloc;
      float a2v = a2[mrow < N_PATCH ? mrow : (N_PATCH - 1)];
      // C/D layout: col = lane&15, row = quad*4 + reg  [m89/m91]
      float best = a2v + b2n[0] - 2.0f * acc[mi][0][r];
#pragma unroll
      for (int ni = 1; ni < 4; ni++)
        best = fminf(best, a2v + b2n[ni] - 2.0f * acc[mi][ni][r]);
      best = fmaxf(best, 0.0f);
#pragma unroll
      for (int s = 1; s < 16; s <<= 1)
        best = fminf(best, __shfl_xor(best, s, 64));
      if (l15 == 0) atomicMin(&smin[rloc], __float_as_uint(best));
    }
  }
  __syncthreads();
  if (t < 128) part[(size_t)ntile * N_PATCH_PAD + m0 + t] = __uint_as_float(smin[t]);
}

// ------------------------------------------------- finalize + collect (last-block fused)
// 25 blocks x 128 threads; thread t owns row b*128+t; coalesced column reads.
// (fence+same-address atomic is fine at 25 blocks; NOT at 1000s — see R6)
__global__ void finalize_collect_kernel(const float* __restrict__ part,
                                        float* __restrict__ min_val, Scal* sc) {
  __shared__ bool last;
  int t = threadIdx.x;
  int row = blockIdx.x * 128 + t;
  float m = FLT_MAX_;
#pragma unroll 8
  for (int nt = 0; nt < NTILES; nt++)
    m = fminf(m, part[(size_t)nt * N_PATCH_PAD + row]);
  if (row < N_PATCH) {
    float v = sqrtf(m);
    min_val[row] = v;
    unsigned long long mp = (((unsigned long long)__float_as_uint(v)) << 32) |
                            (unsigned)(0xffffffffu - (unsigned)row);  // ties -> smaller row
    atomicMax(&sc->approx_max_pack, mp);
  }
  __threadfence();
  __syncthreads();
  if (t == 0) last = (atomicAdd(&sc->done1, 1) == MT - 1);
  __syncthreads();
  if (!last) return;
  __threadfence();
  float amax = __uint_as_float((unsigned)(atomicMax(&sc->approx_max_pack, 0ULL) >> 32));
  for (int i = t; i < N_PATCH; i += 128) {
    if (min_val[i] >= amax - 0.02f) {   // >6 sigma of bf16 noise
      int p = atomicAdd(&sc->cand_count, 1);
      if (p < 64) sc->cand[p] = i;
    }
  }
}

// ------------------------------------------------- exact fp32 refine of candidates
// grid (64 candidates, 128 chunks of 128 rows), block 256 = 4 waves x 32 rows
__global__ void refine_kernel(const float* __restrict__ patch, const float* __restrict__ lib,
                              const float* __restrict__ meanp, const float* __restrict__ stdp,
                              Scal* sc) {
  int c = blockIdx.x;
  int cnt = sc->cand_count; if (cnt > 64) cnt = 64;
  if (c >= cnt) return;
  int row = sc->cand[c];
  int wave = threadIdx.x >> 6, lane = threadIdx.x & 63;
  float mu = meanp[0], sd = stdp[0];
  float4 pv[3];
#pragma unroll
  for (int k = 0; k < 3; k++) {
    float4 v = ((const float4*)(patch + (size_t)row * DIM))[lane + 64 * k];
    v.x = (v.x - mu) / sd; v.y = (v.y - mu) / sd;
    v.z = (v.z - mu) / sd; v.w = (v.w - mu) / sd;
    pv[k] = v;
  }
  unsigned long long best = ~0ULL;
  int jbase = blockIdx.y * 128 + wave * 32;
  for (int rr = 0; rr < 32; rr++) {
    int j = jbase + rr;
    const float4* pl = (const float4*)(lib + (size_t)j * DIM);
    float acc = 0.f;
#pragma unroll
    for (int k = 0; k < 3; k++) {
      float4 l = pl[lane + 64 * k];
      float dx = pv[k].x - l.x, dy = pv[k].y - l.y;
      float dz = pv[k].z - l.z, dw = pv[k].w - l.w;
      acc += dx*dx + dy*dy + dz*dz + dw*dw;
    }
    acc = wave_reduce_sum(acc);
    unsigned long long pk = (((unsigned long long)__float_as_uint(acc)) << 32) | (unsigned)j;
    if (pk < best) best = pk;
  }
  if (lane == 0) atomicMin(&sc->cand_pack[c], best);
}

// inline "pick": wave-level max over candidates
__device__ __forceinline__ void wave_pick(const Scal* sc, int lane,
                                          int* srow, float* sstar, int* ms) {
  int cnt = sc->cand_count; if (cnt > 64) cnt = 64;
  unsigned long long pk = 0ULL;
  int rowv = 0, msv = 0;
  if (lane < cnt) {
    unsigned long long cp = sc->cand_pack[lane];
    rowv = sc->cand[lane];
    msv = (int)(cp & 0xffffffffu);
    pk = (cp & 0xffffffff00000000ULL) | (unsigned)(0xffffffffu - (unsigned)rowv);
  }
  unsigned long long m = pk;
#pragma unroll
  for (int s = 1; s < 64; s <<= 1) {
    unsigned long long o = shfl_xor_u64(m, s);
    if (o > m) m = o;
  }
  unsigned long long mask = __ballot(pk == m && lane < cnt);
  int wl = (int)(__ffsll((long long)mask) - 1);
  *srow = __shfl(rowv, wl, 64);
  *ms   = __shfl(msv, wl, 64);
  *sstar = sqrtf(__uint_as_float((unsigned)(m >> 32)));
}

// ------------------------------------------------- w_dist^2 of m_star to whole bank
// 256 blocks x 256 threads; wave holds m_star row in regs, sweeps 16 lib rows.
__global__ void wdist_kernel(const float* __restrict__ lib, const Scal* __restrict__ sc,
                             float* __restrict__ wdist2) {
  int wave = threadIdx.x >> 6, lane = threadIdx.x & 63;
  int srow_, ms; float ss_;
  wave_pick(sc, lane, &srow_, &ss_, &ms);
  float4 pm[3];
#pragma unroll
  for (int k = 0; k < 3; k++)
    pm[k] = ((const float4*)(lib + (size_t)ms * DIM))[lane + 64 * k];
  int jbase = blockIdx.x * 64 + wave * 16;
  for (int rr = 0; rr < 16; rr++) {
    int j = jbase + rr;
    const float4* pj = (const float4*)(lib + (size_t)j * DIM);
    float acc = 0.f;
#pragma unroll
    for (int k = 0; k < 3; k++) {
      float4 a = pj[lane + 64 * k];
      float dx = a.x - pm[k].x, dy = a.y - pm[k].y;
      float dz = a.z - pm[k].z, dw = a.w - pm[k].w;
      acc += dx*dx + dy*dy + dz*dz + dw*dw;
    }
    acc = wave_reduce_sum(acc);
    if (lane == 0) wdist2[j] = acc;
  }
}

// ------------------------------------------------- top-3 smallest + final scalar s
// 1 block; packed u64 keys (unique -> lax.top_k tie-breaking), wave-parallel merge.
__global__ void top3_kernel(const float* __restrict__ wdist2,
                            const float* __restrict__ patch, const float* __restrict__ lib,
                            const float* __restrict__ meanp, const float* __restrict__ stdp,
                            const Scal* __restrict__ sc, float* __restrict__ out) {
  __shared__ unsigned long long sl[768];
  int t = threadIdx.x;

  unsigned long long b0 = ~0ULL, b1 = ~0ULL, b2 = ~0ULL;
  for (int j = t; j < N_LIB; j += 256) {
    unsigned long long pk = (((unsigned long long)__float_as_uint(wdist2[j])) << 32) | (unsigned)j;
    if (pk < b0)      { b2 = b1; b1 = b0; b0 = pk; }
    else if (pk < b1) { b2 = b1; b1 = pk; }
    else if (pk < b2) { b2 = pk; }
  }
  sl[t * 3 + 0] = b0; sl[t * 3 + 1] = b1; sl[t * 3 + 2] = b2;
  __syncthreads();
  if (t >= 64) return;

  unsigned long long c0 = ~0ULL, c1 = ~0ULL, c2 = ~0ULL;
#pragma unroll
  for (int e = 0; e < 12; e++) {
    unsigned long long pk = sl[t * 12 + e];
    if (pk < c0)      { c2 = c1; c1 = c0; c0 = pk; }
    else if (pk < c1) { c2 = c1; c1 = pk; }
    else if (pk < c2) { c2 = pk; }
  }
  unsigned long long res1 = 0, res2 = 0;
#pragma unroll
  for (int r = 0; r < 3; r++) {
    unsigned long long m = c0;
#pragma unroll
    for (int s = 1; s < 64; s <<= 1) {
      unsigned long long o = shfl_xor_u64(m, s);
      if (o < m) m = o;
    }
    if (r == 1) res1 = m;
    if (r == 2) res2 = m;
    if (c0 == m) { c0 = c1; c1 = c2; c2 = ~0ULL; }
  }
  int nA = (int)(res1 & 0xffffffffu);   // 2nd nearest
  int nB = (int)(res2 & 0xffffffffu);   // 3rd nearest

  int srow, ms2; float sstar;
  wave_pick(sc, t, &srow, &sstar, &ms2);

  float mu = meanp[0], sd = stdp[0];
  float accA = 0.f, accB = 0.f;
#pragma unroll
  for (int k = 0; k < 3; k++) {
    float4 p4 = ((const float4*)(patch + (size_t)srow * DIM))[t + 64 * k];
    float4 a4 = ((const float4*)(lib + (size_t)nA * DIM))[t + 64 * k];
    float4 b4 = ((const float4*)(lib + (size_t)nB * DIM))[t + 64 * k];
    float px = (p4.x - mu) / sd, py = (p4.y - mu) / sd;
    float pz = (p4.z - mu) / sd, pw = (p4.w - mu) / sd;
    float dax = px - a4.x, day = py - a4.y, daz = pz - a4.z, daw = pw - a4.w;
    float dbx = px - b4.x, dby = py - b4.y, dbz = pz - b4.z, dbw = pw - b4.w;
    accA += dax*dax + day*day + daz*daz + daw*daw;
    accB += dbx*dbx + dby*dby + dbz*dbz + dbw*dbw;
  }
  accA = wave_reduce_sum(accA);
  accB = wave_reduce_sum(accB);
  if (t == 0) {
    float dsq = sqrtf((float)DIM);
    float d1 = sqrtf(accA), d2v = sqrtf(accB);
    float w = 1.0f - expf(sstar / dsq) / (expf(d1 / dsq) + expf(d2v / dsq));
    out[0] = w * sstar;
  }
}

// ------------------------------------------------- fused bilinear 56->224 + 9x9 blur
// 49 blocks, 256 threads; block = 32x32 output tile; 40x40 resized halo in LDS.
// NOTE: `out` already points at d_out+1 (map base).
__global__ void resize_blur_kernel(const float* __restrict__ mv, float* __restrict__ out) {
  __shared__ float rs[40 * 40];
  int bx = blockIdx.x % 7, by = blockIdx.x / 7;
  int ox0 = bx * 32, oy0 = by * 32;
  int t = threadIdx.x;

  for (int i = t; i < 1600; i += 256) {
    int ly = i / 40, lx = i % 40;
    int gy = oy0 - 4 + ly; gy = gy < 0 ? 0 : (gy > 223 ? 223 : gy);
    int gx = ox0 - 4 + lx; gx = gx < 0 ? 0 : (gx > 223 ? 223 : gx);
    float sy = fminf(fmaxf(0.25f * gy - 0.375f, 0.0f), 55.0f);
    float sx = fminf(fmaxf(0.25f * gx - 0.375f, 0.0f), 55.0f);
    int y0 = (int)sy; if (y0 > 54) y0 = 54;
    int x0 = (int)sx; if (x0 > 54) x0 = 54;
    float fy = sy - y0, fx = sx - x0;
    float v00 = mv[y0*FM + x0],     v01 = mv[y0*FM + x0 + 1];
    float v10 = mv[(y0+1)*FM + x0], v11 = mv[(y0+1)*FM + x0 + 1];
    float a = v00 + fx * (v01 - v00);
    float b = v10 + fx * (v11 - v10);
    rs[i] = a + fy * (b - a);
  }
  __syncthreads();

  float g[9]; float gs = 0.f;
#pragma unroll
  for (int i = 0; i < 9; i++) { float tt = (float)(i - 4); g[i] = expf(-(tt*tt)/32.0f); gs += g[i]; }
#pragma unroll
  for (int i = 0; i < 9; i++) g[i] /= gs;

  for (int p = t; p < 1024; p += 256) {
    int y = oy0 + p / 32, x = ox0 + (p & 31);
    float acc = 0.f;
#pragma unroll
    for (int dy = 0; dy < 9; dy++) {
      int yy = y + dy - 4;
      yy = yy < 0 ? -yy : (yy > IMGSZ - 1 ? 2*(IMGSZ-1) - yy : yy);
      int lyy = yy - (oy0 - 4);
      float ra = 0.f;
#pragma unroll
      for (int dx = 0; dx < 9; dx++) {
        int xx = x + dx - 4;
        xx = xx < 0 ? -xx : (xx > IMGSZ - 1 ? 2*(IMGSZ-1) - xx : xx);
        ra += g[dx] * rs[lyy * 40 + (xx - (ox0 - 4))];
      }
      acc += g[dy] * ra;
    }
    out[y * IMGSZ + x] = acc;
  }
}

// ================================================= host
extern "C" void kernel_launch(void* const* d_in, const int* in_sizes, int n_in,
                              void* d_out, int out_size, void* d_ws, size_t ws_size,
                              hipStream_t stream) {
  const float* patch = (const float*)d_in[0];
  const float* lib   = (const float*)d_in[1];
  const float* meanp = (const float*)d_in[2];
  const float* stdp  = (const float*)d_in[3];
  float* out = (float*)d_out;

  char* ws = (char*)d_ws;
  size_t off = 0;
  auto alloc = [&](size_t bytes) -> void* {
    void* p = ws + off;
    off = (off + bytes + 255) & ~(size_t)255;
    return p;
  };
  bf16_t* pb      = (bf16_t*)alloc((size_t)N_PATCH * DIM * sizeof(bf16_t));
  bf16_t* lb      = (bf16_t*)alloc((size_t)N_LIB * DIM * sizeof(bf16_t));
  float* a2       = (float*)alloc(N_PATCH * sizeof(float));
  float* b2       = (float*)alloc(N_LIB * sizeof(float));
  float* part     = (float*)alloc((size_t)N_PATCH_PAD * NTILES * sizeof(float));
  float* min_val  = (float*)alloc(N_PATCH * sizeof(float));
  float* wdist2   = (float*)alloc(N_LIB * sizeof(float));
  Scal*  sc       = (Scal*)alloc(sizeof(Scal));

  prep_kernel<<<N_PATCH / 4 + N_LIB / 4, 256, 0, stream>>>(patch, lib, meanp, stdp,
                                                           pb, lb, a2, b2, sc);
  gemm_min_kernel<<<MT * NTILES, 256, 0, stream>>>(pb, lb, a2, b2, part);
  finalize_collect_kernel<<<MT, 128, 0, stream>>>(part, min_val, sc);
  refine_kernel<<<dim3(64, 128), 256, 0, stream>>>(patch, lib, meanp, stdp, sc);
  wdist_kernel<<<256, 256, 0, stream>>>(lib, sc, wdist2);
  top3_kernel<<<1, 256, 0, stream>>>(wdist2, patch, lib, meanp, stdp, sc, out);
  resize_blur_kernel<<<49, 256, 0, stream>>>(min_val, out + 1);
}

// Round 9
// 353.584 us; speedup vs baseline: 1.9737x; 1.0394x over previous
//
#include <hip/hip_runtime.h>
#include <hip/hip_bf16.h>
#include <stdint.h>

// Problem constants
#define N_PATCH 3136     // 56*56 query rows
#define N_PATCH_PAD 3200 // 25 m-tiles * 128
#define N_LIB   16384    // memory bank rows
#define DIM     768
#define IMGSZ   224
#define FM      56

// GEMM tiling
#define BK 32
#define KT 24            // DIM/BK
#define MT 25            // m-tiles
#define NTILES 128       // n-tiles (16384/128)

// tail kernel: 64 blocks <= 256 CUs -> always co-resident (manual grid barrier safe)
#define TAILB 64

typedef __bf16 bf16_t;
typedef __bf16 bf16x8 __attribute__((ext_vector_type(8)));
typedef __bf16 bf16x4_v __attribute__((ext_vector_type(4)));
typedef float  f32x4  __attribute__((ext_vector_type(4)));

#define FLT_MAX_ 3.402823466e+38f

struct Scal {
  unsigned long long approx_max_pack;   // (bits(sqrt-min)<<32) | (0xffffffff - row)
  unsigned long long cand_pack[64];     // per-candidate exact (bits(d2)<<32)|argmin_j
  int cand[64];
  int cand_count;
  int bar[4];                           // grid-barrier counters (one-shot each)
};

__device__ __forceinline__ float wave_reduce_sum(float v) {
#pragma unroll
  for (int s = 32; s > 0; s >>= 1) v += __shfl_xor(v, s, 64);
  return v;
}

__device__ __forceinline__ unsigned long long shfl_xor_u64(unsigned long long v, int mask) {
  unsigned lo = (unsigned)v, hi = (unsigned)(v >> 32);
  lo = __shfl_xor(lo, mask, 64);
  hi = __shfl_xor(hi, mask, 64);
  return ((unsigned long long)hi << 32) | lo;
}

// async global->LDS, 16B per lane; LDS dest = wave-uniform base + lane*size
__device__ __forceinline__ void async16(const bf16_t* g, bf16_t* l) {
  __builtin_amdgcn_global_load_lds(
      (const __attribute__((address_space(1))) unsigned int*)g,
      (__attribute__((address_space(3))) unsigned int*)l, 16, 0, 0);
}

// software grid barrier (rocPRIM pattern); REQUIRES all blocks co-resident.
// 64 blocks on 256 CUs => structurally guaranteed.
__device__ __forceinline__ void grid_bar(int* ctr, int nb) {
  __syncthreads();                       // all block's mem ops complete (vmcnt drain)
  if (threadIdx.x == 0) {
    __threadfence();                     // release: writeback to coherence point
    atomicAdd(ctr, 1);
    while (atomicAdd(ctr, 0) < nb) __builtin_amdgcn_s_sleep(8);
    __threadfence();                     // acquire: invalidate L1/L2
  }
  __syncthreads();
}

// ------------------------------------------------- prep: normalize + bf16 + norms
// blocks [0,784): patch rows (wave per row); blocks [784, 784+4096): lib rows
__global__ void prep_kernel(const float* __restrict__ patch, const float* __restrict__ lib,
                            const float* __restrict__ meanp, const float* __restrict__ stdp,
                            bf16_t* __restrict__ pb, bf16_t* __restrict__ lb,
                            float* __restrict__ a2, float* __restrict__ b2, Scal* sc) {
  int t = threadIdx.x;
  int lane = t & 63;
  if (blockIdx.x == 0) {  // init (stream order guarantees this runs before consumers)
    if (t < 64) sc->cand_pack[t] = ~0ULL;
    if (t == 64) { sc->approx_max_pack = 0ULL; sc->cand_count = 0; }
    if (t >= 65 && t < 69) sc->bar[t - 65] = 0;
  }
  if (blockIdx.x < N_PATCH / 4) {
    int row = blockIdx.x * 4 + (t >> 6);
    float mu = meanp[0], sd = stdp[0];
    float acc = 0.f;
#pragma unroll
    for (int k = 0; k < 3; k++) {
      float4 v = ((const float4*)(patch + (size_t)row * DIM))[lane + 64 * k];
      v.x = (v.x - mu) / sd; v.y = (v.y - mu) / sd;
      v.z = (v.z - mu) / sd; v.w = (v.w - mu) / sd;
      bf16x4_v o = {(__bf16)v.x, (__bf16)v.y, (__bf16)v.z, (__bf16)v.w};
      *(bf16x4_v*)(pb + (size_t)row * DIM + (lane + 64 * k) * 4) = o;
      acc += v.x*v.x + v.y*v.y + v.z*v.z + v.w*v.w;
    }
    acc = wave_reduce_sum(acc);
    if (lane == 0) a2[row] = acc;
  } else {
    int row = (blockIdx.x - N_PATCH / 4) * 4 + (t >> 6);
    float acc = 0.f;
#pragma unroll
    for (int k = 0; k < 3; k++) {
      float4 v = ((const float4*)(lib + (size_t)row * DIM))[lane + 64 * k];
      bf16x4_v o = {(__bf16)v.x, (__bf16)v.y, (__bf16)v.z, (__bf16)v.w};
      *(bf16x4_v*)(lb + (size_t)row * DIM + (lane + 64 * k) * 4) = o;
      acc += v.x*v.x + v.y*v.y + v.z*v.z + v.w*v.w;
    }
    acc = wave_reduce_sum(acc);
    if (lane == 0) b2[row] = acc;
  }
}

// ------------------------------------------------- fused bf16 GEMM + row-min
// 3200 blocks (XCD-swizzled), 256 threads = 4 waves; block tile 128(M) x 128(N),
// global_load_lds width-16 staging, LDS double buffer, one barrier per K-step.
// Epilogue: float-only row min -> part[ntile][row] (coalesced).
__global__ __launch_bounds__(256, 3)
void gemm_min_kernel(const bf16_t* __restrict__ pb, const bf16_t* __restrict__ lb,
                     const float* __restrict__ a2, const float* __restrict__ b2,
                     float* __restrict__ part) {
  __shared__ __align__(16) bf16_t As[2][128 * BK];
  __shared__ __align__(16) bf16_t Bs[2][128 * BK];
  __shared__ unsigned smin[128];

  const int t = threadIdx.x;
  const int wave = t >> 6;
  const int lane = t & 63;
  const int l15 = lane & 15;
  const int quad = lane >> 4;
  const int wm = (wave >> 1) * 64;
  const int wn = (wave & 1) * 64;

  // XCD swizzle: one XCD owns 16 consecutive-mod-8 ntiles -> lb slice ~3MB L2-resident
  const int lid = blockIdx.x;
  const int xcd = lid & 7;
  const int slot = lid >> 3;               // 0..399
  const int ntile = xcd + 8 * (slot / MT); // 0..127
  const int mtile = slot % MT;
  const int m0 = mtile * 128;
  const int n0 = ntile * 128;

  int ra0 = m0 + (t >> 2);       if (ra0 > N_PATCH - 1) ra0 = N_PATCH - 1;
  int ra1 = m0 + 64 + (t >> 2);  if (ra1 > N_PATCH - 1) ra1 = N_PATCH - 1;
  const bf16_t* gA0 = pb + (size_t)ra0 * DIM + (t & 3) * 8;
  const bf16_t* gA1 = pb + (size_t)ra1 * DIM + (t & 3) * 8;
  const bf16_t* gB0 = lb + (size_t)(n0 + (t >> 2)) * DIM + (t & 3) * 8;
  const bf16_t* gB1 = gB0 + (size_t)64 * DIM;

  if (t < 128) smin[t] = 0xffffffffu;

  {
    bf16_t* la = &As[0][0];
    bf16_t* lb_ = &Bs[0][0];
    async16(gA0, la + t * 8);
    async16(gA1, la + 2048 + t * 8);
    async16(gB0, lb_ + t * 8);
    async16(gB1, lb_ + 2048 + t * 8);
  }
  __syncthreads();

  f32x4 acc[4][4];
#pragma unroll
  for (int mi = 0; mi < 4; mi++)
#pragma unroll
    for (int ni = 0; ni < 4; ni++) { f32x4 z = {0.f,0.f,0.f,0.f}; acc[mi][ni] = z; }

  for (int k = 0; k < KT; ++k) {
    const int cur = k & 1;
    if (k + 1 < KT) {
      const int nxt = cur ^ 1;
      const size_t ko = (size_t)(k + 1) * BK;
      bf16_t* la = &As[nxt][0];
      bf16_t* lb_ = &Bs[nxt][0];
      async16(gA0 + ko, la + t * 8);
      async16(gA1 + ko, la + 2048 + t * 8);
      async16(gB0 + ko, lb_ + t * 8);
      async16(gB1 + ko, lb_ + 2048 + t * 8);
    }

    bf16x8 afr[4], bfr[4];
#pragma unroll
    for (int mi = 0; mi < 4; mi++)
      afr[mi] = *(const bf16x8*)(&As[cur][(wm + mi * 16 + l15) * BK + quad * 8]);
#pragma unroll
    for (int ni = 0; ni < 4; ni++)
      bfr[ni] = *(const bf16x8*)(&Bs[cur][(wn + ni * 16 + l15) * BK + quad * 8]);
#pragma unroll
    for (int mi = 0; mi < 4; mi++)
#pragma unroll
      for (int ni = 0; ni < 4; ni++)
        acc[mi][ni] = __builtin_amdgcn_mfma_f32_16x16x32_bf16(afr[mi], bfr[ni],
                                                              acc[mi][ni], 0, 0, 0);
    __syncthreads();
  }

  // epilogue: d2 = a2 + b2 - 2*dot; float-only min (no index)
  float b2n[4];
#pragma unroll
  for (int ni = 0; ni < 4; ni++) b2n[ni] = b2[n0 + wn + ni * 16 + l15];

#pragma unroll
  for (int mi = 0; mi < 4; mi++) {
#pragma unroll
    for (int r = 0; r < 4; r++) {
      int rloc = wm + mi * 16 + quad * 4 + r;
      int mrow = m0 + rloc;
      float a2v = a2[mrow < N_PATCH ? mrow : (N_PATCH - 1)];
      // C/D layout: col = lane&15, row = quad*4 + reg  [m89/m91]
      float best = a2v + b2n[0] - 2.0f * acc[mi][0][r];
#pragma unroll
      for (int ni = 1; ni < 4; ni++)
        best = fminf(best, a2v + b2n[ni] - 2.0f * acc[mi][ni][r]);
      best = fmaxf(best, 0.0f);
#pragma unroll
      for (int s = 1; s < 16; s <<= 1)
        best = fminf(best, __shfl_xor(best, s, 64));
      if (l15 == 0) atomicMin(&smin[rloc], __float_as_uint(best));
    }
  }
  __syncthreads();
  if (t < 128) part[(size_t)ntile * N_PATCH_PAD + m0 + t] = __uint_as_float(smin[t]);
}

// inline "pick": wave-level max over candidates
__device__ __forceinline__ void wave_pick(const Scal* sc, int cnt, int lane,
                                          int* srow, float* sstar, int* ms) {
  unsigned long long pk = 0ULL;
  int rowv = 0, msv = 0;
  if (lane < cnt) {
    unsigned long long cp = sc->cand_pack[lane];
    rowv = sc->cand[lane];
    msv = (int)(cp & 0xffffffffu);
    pk = (cp & 0xffffffff00000000ULL) | (unsigned)(0xffffffffu - (unsigned)rowv);
  }
  unsigned long long m = pk;
#pragma unroll
  for (int s = 1; s < 64; s <<= 1) {
    unsigned long long o = shfl_xor_u64(m, s);
    if (o > m) m = o;
  }
  unsigned long long mask = __ballot(pk == m && lane < cnt);
  int wl = (int)(__ffsll((long long)mask) - 1);
  *srow = __shfl(rowv, wl, 64);
  *ms   = __shfl(msv, wl, 64);
  *sstar = sqrtf(__uint_as_float((unsigned)(m >> 32)));
}

// ------------------------------------------------- tail (single dispatch, 64 blocks):
// P0 finalize -> bar -> P1 collect -> bar -> P2 refine -> bar -> P3 wdist -> bar ->
// P4 (top3+s on block 0 || resize+blur on blocks 1..49)
__global__ __launch_bounds__(256, 2)
void tail_kernel(const float* __restrict__ part, float* __restrict__ min_val,
                 const float* __restrict__ patch, const float* __restrict__ lib,
                 const float* __restrict__ meanp, const float* __restrict__ stdp,
                 Scal* __restrict__ sc, float* __restrict__ wdist2,
                 float* __restrict__ out0, float* __restrict__ outmap) {
  __shared__ union {
    unsigned long long sl[768];   // top3
    float rs[40 * 40];            // resize halo
  } sm;
  __shared__ int s_cnt;

  const int t = threadIdx.x;
  const int b = blockIdx.x;
  const int wave = t >> 6, lane = t & 63;

  // ---- P0: finalize (blocks 0..12 cover 3136 rows; coalesced column reads) ----
  {
    int row = b * 256 + t;
    if (row < N_PATCH) {
      float m = FLT_MAX_;
#pragma unroll 8
      for (int nt = 0; nt < NTILES; nt++)
        m = fminf(m, part[(size_t)nt * N_PATCH_PAD + row]);
      float v = sqrtf(m);
      min_val[row] = v;
      unsigned long long mp = (((unsigned long long)__float_as_uint(v)) << 32) |
                              (unsigned)(0xffffffffu - (unsigned)row);  // ties -> smaller row
      atomicMax(&sc->approx_max_pack, mp);
    }
  }
  grid_bar(&sc->bar[0], TAILB);

  // ---- P1: collect candidates (block 0) ----
  if (b == 0) {
    float amax = __uint_as_float((unsigned)(atomicMax(&sc->approx_max_pack, 0ULL) >> 32));
    for (int i = t; i < N_PATCH; i += 256) {
      if (min_val[i] >= amax - 0.02f) {   // >6 sigma of bf16 noise
        int p = atomicAdd(&sc->cand_count, 1);
        if (p < 64) sc->cand[p] = i;
      }
    }
  }
  grid_bar(&sc->bar[1], TAILB);

  if (t == 0) s_cnt = atomicAdd(&sc->cand_count, 0);
  __syncthreads();
  int cnt = s_cnt; if (cnt > 64) cnt = 64;

  // ---- P2: exact fp32 refine (64 blocks x 256 lib rows, per candidate) ----
  {
    float mu = meanp[0], sd = stdp[0];
    for (int c = 0; c < cnt; c++) {
      int row = sc->cand[c];
      float4 pv[3];
#pragma unroll
      for (int k = 0; k < 3; k++) {
        float4 v = ((const float4*)(patch + (size_t)row * DIM))[lane + 64 * k];
        v.x = (v.x - mu) / sd; v.y = (v.y - mu) / sd;
        v.z = (v.z - mu) / sd; v.w = (v.w - mu) / sd;
        pv[k] = v;
      }
      unsigned long long best = ~0ULL;
      int jbase = b * 256 + wave * 64;
      for (int rr = 0; rr < 64; rr++) {
        int j = jbase + rr;
        const float4* pl = (const float4*)(lib + (size_t)j * DIM);
        float acc = 0.f;
#pragma unroll
        for (int k = 0; k < 3; k++) {
          float4 l = pl[lane + 64 * k];
          float dx = pv[k].x - l.x, dy = pv[k].y - l.y;
          float dz = pv[k].z - l.z, dw = pv[k].w - l.w;
          acc += dx*dx + dy*dy + dz*dz + dw*dw;
        }
        acc = wave_reduce_sum(acc);
        unsigned long long pk = (((unsigned long long)__float_as_uint(acc)) << 32) | (unsigned)j;
        if (pk < best) best = pk;
      }
      if (lane == 0) atomicMin(&sc->cand_pack[c], best);
    }
  }
  grid_bar(&sc->bar[2], TAILB);

  // ---- P3: wdist (64 blocks x 256 rows; wave holds m_star in regs) ----
  {
    int srow_, ms; float ss_;
    wave_pick(sc, cnt, lane, &srow_, &ss_, &ms);
    float4 pm[3];
#pragma unroll
    for (int k = 0; k < 3; k++)
      pm[k] = ((const float4*)(lib + (size_t)ms * DIM))[lane + 64 * k];
    int jbase = b * 256 + wave * 64;
    for (int rr = 0; rr < 64; rr++) {
      int j = jbase + rr;
      const float4* pj = (const float4*)(lib + (size_t)j * DIM);
      float acc = 0.f;
#pragma unroll
      for (int k = 0; k < 3; k++) {
        float4 a = pj[lane + 64 * k];
        float dx = a.x - pm[k].x, dy = a.y - pm[k].y;
        float dz = a.z - pm[k].z, dw = a.w - pm[k].w;
        acc += dx*dx + dy*dy + dz*dz + dw*dw;
      }
      acc = wave_reduce_sum(acc);
      if (lane == 0) wdist2[j] = acc;
    }
  }
  grid_bar(&sc->bar[3], TAILB);

  // ---- P4a: top3 + scalar s (block 0) ----
  if (b == 0) {
    unsigned long long b0 = ~0ULL, b1 = ~0ULL, b2 = ~0ULL;
    for (int j = t; j < N_LIB; j += 256) {
      unsigned long long pk = (((unsigned long long)__float_as_uint(wdist2[j])) << 32) | (unsigned)j;
      if (pk < b0)      { b2 = b1; b1 = b0; b0 = pk; }
      else if (pk < b1) { b2 = b1; b1 = pk; }
      else if (pk < b2) { b2 = pk; }
    }
    sm.sl[t * 3 + 0] = b0; sm.sl[t * 3 + 1] = b1; sm.sl[t * 3 + 2] = b2;
    __syncthreads();
    if (t >= 64) return;

    unsigned long long c0 = ~0ULL, c1 = ~0ULL, c2 = ~0ULL;
#pragma unroll
    for (int e = 0; e < 12; e++) {
      unsigned long long pk = sm.sl[t * 12 + e];
      if (pk < c0)      { c2 = c1; c1 = c0; c0 = pk; }
      else if (pk < c1) { c2 = c1; c1 = pk; }
      else if (pk < c2) { c2 = pk; }
    }
    unsigned long long res1 = 0, res2 = 0;
#pragma unroll
    for (int r = 0; r < 3; r++) {
      unsigned long long m = c0;
#pragma unroll
      for (int s = 1; s < 64; s <<= 1) {
        unsigned long long o = shfl_xor_u64(m, s);
        if (o < m) m = o;
      }
      if (r == 1) res1 = m;
      if (r == 2) res2 = m;
      if (c0 == m) { c0 = c1; c1 = c2; c2 = ~0ULL; }
    }
    int nA = (int)(res1 & 0xffffffffu);   // 2nd nearest
    int nB = (int)(res2 & 0xffffffffu);   // 3rd nearest

    int srow, ms2; float sstar;
    wave_pick(sc, cnt, t, &srow, &sstar, &ms2);

    float mu = meanp[0], sd = stdp[0];
    float accA = 0.f, accB = 0.f;
#pragma unroll
    for (int k = 0; k < 3; k++) {
      float4 p4 = ((const float4*)(patch + (size_t)srow * DIM))[t + 64 * k];
      float4 a4 = ((const float4*)(lib + (size_t)nA * DIM))[t + 64 * k];
      float4 b4 = ((const float4*)(lib + (size_t)nB * DIM))[t + 64 * k];
      float px = (p4.x - mu) / sd, py = (p4.y - mu) / sd;
      float pz = (p4.z - mu) / sd, pw = (p4.w - mu) / sd;
      float dax = px - a4.x, day = py - a4.y, daz = pz - a4.z, daw = pw - a4.w;
      float dbx = px - b4.x, dby = py - b4.y, dbz = pz - b4.z, dbw = pw - b4.w;
      accA += dax*dax + day*day + daz*daz + daw*daw;
      accB += dbx*dbx + dby*dby + dbz*dbz + dbw*dbw;
    }
    accA = wave_reduce_sum(accA);
    accB = wave_reduce_sum(accB);
    if (t == 0) {
      float dsq = sqrtf((float)DIM);
      float d1 = sqrtf(accA), d2v = sqrtf(accB);
      float w = 1.0f - expf(sstar / dsq) / (expf(d1 / dsq) + expf(d2v / dsq));
      out0[0] = w * sstar;
    }
    return;
  }

  // ---- P4b: fused bilinear 56->224 + 9x9 blur (blocks 1..49) ----
  if (b > 49) return;
  {
    int tile = b - 1;
    int bx = tile % 7, by = tile / 7;
    int ox0 = bx * 32, oy0 = by * 32;

    for (int i = t; i < 1600; i += 256) {
      int ly = i / 40, lx = i % 40;
      int gy = oy0 - 4 + ly; gy = gy < 0 ? 0 : (gy > 223 ? 223 : gy);
      int gx = ox0 - 4 + lx; gx = gx < 0 ? 0 : (gx > 223 ? 223 : gx);
      float sy = fminf(fmaxf(0.25f * gy - 0.375f, 0.0f), 55.0f);
      float sx = fminf(fmaxf(0.25f * gx - 0.375f, 0.0f), 55.0f);
      int y0 = (int)sy; if (y0 > 54) y0 = 54;
      int x0 = (int)sx; if (x0 > 54) x0 = 54;
      float fy = sy - y0, fx = sx - x0;
      float v00 = min_val[y0*FM + x0],     v01 = min_val[y0*FM + x0 + 1];
      float v10 = min_val[(y0+1)*FM + x0], v11 = min_val[(y0+1)*FM + x0 + 1];
      float a = v00 + fx * (v01 - v00);
      float bb = v10 + fx * (v11 - v10);
      sm.rs[i] = a + fy * (bb - a);
    }
    __syncthreads();

    float g[9]; float gs = 0.f;
#pragma unroll
    for (int i = 0; i < 9; i++) { float tt = (float)(i - 4); g[i] = expf(-(tt*tt)/32.0f); gs += g[i]; }
#pragma unroll
    for (int i = 0; i < 9; i++) g[i] /= gs;

    for (int p = t; p < 1024; p += 256) {
      int y = oy0 + p / 32, x = ox0 + (p & 31);
      float acc = 0.f;
#pragma unroll
      for (int dy = 0; dy < 9; dy++) {
        int yy = y + dy - 4;
        yy = yy < 0 ? -yy : (yy > IMGSZ - 1 ? 2*(IMGSZ-1) - yy : yy);
        int lyy = yy - (oy0 - 4);
        float ra = 0.f;
#pragma unroll
        for (int dx = 0; dx < 9; dx++) {
          int xx = x + dx - 4;
          xx = xx < 0 ? -xx : (xx > IMGSZ - 1 ? 2*(IMGSZ-1) - xx : xx);
          ra += g[dx] * sm.rs[lyy * 40 + (xx - (ox0 - 4))];
        }
        acc += g[dy] * ra;
      }
      outmap[y * IMGSZ + x] = acc;
    }
  }
}

// ================================================= host
extern "C" void kernel_launch(void* const* d_in, const int* in_sizes, int n_in,
                              void* d_out, int out_size, void* d_ws, size_t ws_size,
                              hipStream_t stream) {
  const float* patch = (const float*)d_in[0];
  const float* lib   = (const float*)d_in[1];
  const float* meanp = (const float*)d_in[2];
  const float* stdp  = (const float*)d_in[3];
  float* out = (float*)d_out;

  char* ws = (char*)d_ws;
  size_t off = 0;
  auto alloc = [&](size_t bytes) -> void* {
    void* p = ws + off;
    off = (off + bytes + 255) & ~(size_t)255;
    return p;
  };
  bf16_t* pb      = (bf16_t*)alloc((size_t)N_PATCH * DIM * sizeof(bf16_t));
  bf16_t* lb      = (bf16_t*)alloc((size_t)N_LIB * DIM * sizeof(bf16_t));
  float* a2       = (float*)alloc(N_PATCH * sizeof(float));
  float* b2       = (float*)alloc(N_LIB * sizeof(float));
  float* part     = (float*)alloc((size_t)N_PATCH_PAD * NTILES * sizeof(float));
  float* min_val  = (float*)alloc(N_PATCH * sizeof(float));
  float* wdist2   = (float*)alloc(N_LIB * sizeof(float));
  Scal*  sc       = (Scal*)alloc(sizeof(Scal));

  prep_kernel<<<N_PATCH / 4 + N_LIB / 4, 256, 0, stream>>>(patch, lib, meanp, stdp,
                                                           pb, lb, a2, b2, sc);
  gemm_min_kernel<<<MT * NTILES, 256, 0, stream>>>(pb, lb, a2, b2, part);
  tail_kernel<<<TAILB, 256, 0, stream>>>(part, min_val, patch, lib, meanp, stdp,
                                         sc, wdist2, out, out + 1);
}

// Round 10
// 320.004 us; speedup vs baseline: 2.1808x; 1.1049x over previous
//
#include <hip/hip_runtime.h>
#include <hip/hip_bf16.h>
#include <stdint.h>

// Problem constants
#define N_PATCH 3136     // 56*56 query rows
#define N_PATCH_PAD 3200 // 25 m-tiles * 128
#define N_LIB   16384    // memory bank rows
#define DIM     768
#define IMGSZ   224
#define FM      56

// GEMM tiling
#define BK 32
#define KT 24            // DIM/BK
#define MT 25            // m-tiles
#define NTILES 128       // n-tiles (16384/128)

// tail kernel: 64 blocks <= 256 CUs -> always co-resident (manual grid barrier safe)
#define TAILB 64
#define D2_MARGIN 8.0f   // ~24 sigma of bf16 d2 noise: tiles within this of best get fp32 rescan

typedef __bf16 bf16_t;
typedef __bf16 bf16x8 __attribute__((ext_vector_type(8)));
typedef __bf16 bf16x4_v __attribute__((ext_vector_type(4)));
typedef float  f32x4  __attribute__((ext_vector_type(4)));

#define FLT_MAX_ 3.402823466e+38f

struct Scal {
  unsigned long long approx_max_pack;   // (bits(sqrt-min)<<32) | (0xffffffff - row)
  unsigned long long cand_pack[64];     // per-candidate exact (bits(d2)<<32)|argmin_j
  int cand[64];
  int cand_count;
  int bar[4];                           // grid-barrier counters (one-shot each)
};

__device__ __forceinline__ float wave_reduce_sum(float v) {
#pragma unroll
  for (int s = 32; s > 0; s >>= 1) v += __shfl_xor(v, s, 64);
  return v;
}

__device__ __forceinline__ float wave_reduce_min(float v) {
#pragma unroll
  for (int s = 32; s > 0; s >>= 1) v = fminf(v, __shfl_xor(v, s, 64));
  return v;
}

__device__ __forceinline__ unsigned long long shfl_xor_u64(unsigned long long v, int mask) {
  unsigned lo = (unsigned)v, hi = (unsigned)(v >> 32);
  lo = __shfl_xor(lo, mask, 64);
  hi = __shfl_xor(hi, mask, 64);
  return ((unsigned long long)hi << 32) | lo;
}

// async global->LDS, 16B per lane; LDS dest = wave-uniform base + lane*size
__device__ __forceinline__ void async16(const bf16_t* g, bf16_t* l) {
  __builtin_amdgcn_global_load_lds(
      (const __attribute__((address_space(1))) unsigned int*)g,
      (__attribute__((address_space(3))) unsigned int*)l, 16, 0, 0);
}

// software grid barrier (rocPRIM pattern); REQUIRES all blocks co-resident.
__device__ __forceinline__ void grid_bar(int* ctr, int nb) {
  __syncthreads();
  if (threadIdx.x == 0) {
    __threadfence();
    atomicAdd(ctr, 1);
    while (atomicAdd(ctr, 0) < nb) __builtin_amdgcn_s_sleep(8);
    __threadfence();
  }
  __syncthreads();
}

__device__ __forceinline__ float bf16u_to_f(unsigned short u) {
  return __uint_as_float(((unsigned)u) << 16);
}

// ------------------------------------------------- prep: normalize + bf16 + norms
__global__ void prep_kernel(const float* __restrict__ patch, const float* __restrict__ lib,
                            const float* __restrict__ meanp, const float* __restrict__ stdp,
                            bf16_t* __restrict__ pb, bf16_t* __restrict__ lb,
                            float* __restrict__ a2, float* __restrict__ b2, Scal* sc) {
  int t = threadIdx.x;
  int lane = t & 63;
  if (blockIdx.x == 0) {
    if (t < 64) sc->cand_pack[t] = ~0ULL;
    if (t == 64) { sc->approx_max_pack = 0ULL; sc->cand_count = 0; }
    if (t >= 65 && t < 69) sc->bar[t - 65] = 0;
  }
  if (blockIdx.x < N_PATCH / 4) {
    int row = blockIdx.x * 4 + (t >> 6);
    float mu = meanp[0], sd = stdp[0];
    float acc = 0.f;
#pragma unroll
    for (int k = 0; k < 3; k++) {
      float4 v = ((const float4*)(patch + (size_t)row * DIM))[lane + 64 * k];
      v.x = (v.x - mu) / sd; v.y = (v.y - mu) / sd;
      v.z = (v.z - mu) / sd; v.w = (v.w - mu) / sd;
      bf16x4_v o = {(__bf16)v.x, (__bf16)v.y, (__bf16)v.z, (__bf16)v.w};
      *(bf16x4_v*)(pb + (size_t)row * DIM + (lane + 64 * k) * 4) = o;
      acc += v.x*v.x + v.y*v.y + v.z*v.z + v.w*v.w;
    }
    acc = wave_reduce_sum(acc);
    if (lane == 0) a2[row] = acc;
  } else {
    int row = (blockIdx.x - N_PATCH / 4) * 4 + (t >> 6);
    float acc = 0.f;
#pragma unroll
    for (int k = 0; k < 3; k++) {
      float4 v = ((const float4*)(lib + (size_t)row * DIM))[lane + 64 * k];
      bf16x4_v o = {(__bf16)v.x, (__bf16)v.y, (__bf16)v.z, (__bf16)v.w};
      *(bf16x4_v*)(lb + (size_t)row * DIM + (lane + 64 * k) * 4) = o;
      acc += v.x*v.x + v.y*v.y + v.z*v.z + v.w*v.w;
    }
    acc = wave_reduce_sum(acc);
    if (lane == 0) b2[row] = acc;
  }
}

// ------------------------------------------------- fused bf16 GEMM + row-min (unchanged R9)
__global__ __launch_bounds__(256, 3)
void gemm_min_kernel(const bf16_t* __restrict__ pb, const bf16_t* __restrict__ lb,
                     const float* __restrict__ a2, const float* __restrict__ b2,
                     float* __restrict__ part) {
  __shared__ __align__(16) bf16_t As[2][128 * BK];
  __shared__ __align__(16) bf16_t Bs[2][128 * BK];
  __shared__ unsigned smin[128];

  const int t = threadIdx.x;
  const int wave = t >> 6;
  const int lane = t & 63;
  const int l15 = lane & 15;
  const int quad = lane >> 4;
  const int wm = (wave >> 1) * 64;
  const int wn = (wave & 1) * 64;

  const int lid = blockIdx.x;
  const int xcd = lid & 7;
  const int slot = lid >> 3;
  const int ntile = xcd + 8 * (slot / MT);
  const int mtile = slot % MT;
  const int m0 = mtile * 128;
  const int n0 = ntile * 128;

  int ra0 = m0 + (t >> 2);       if (ra0 > N_PATCH - 1) ra0 = N_PATCH - 1;
  int ra1 = m0 + 64 + (t >> 2);  if (ra1 > N_PATCH - 1) ra1 = N_PATCH - 1;
  const bf16_t* gA0 = pb + (size_t)ra0 * DIM + (t & 3) * 8;
  const bf16_t* gA1 = pb + (size_t)ra1 * DIM + (t & 3) * 8;
  const bf16_t* gB0 = lb + (size_t)(n0 + (t >> 2)) * DIM + (t & 3) * 8;
  const bf16_t* gB1 = gB0 + (size_t)64 * DIM;

  if (t < 128) smin[t] = 0xffffffffu;

  {
    bf16_t* la = &As[0][0];
    bf16_t* lb_ = &Bs[0][0];
    async16(gA0, la + t * 8);
    async16(gA1, la + 2048 + t * 8);
    async16(gB0, lb_ + t * 8);
    async16(gB1, lb_ + 2048 + t * 8);
  }
  __syncthreads();

  f32x4 acc[4][4];
#pragma unroll
  for (int mi = 0; mi < 4; mi++)
#pragma unroll
    for (int ni = 0; ni < 4; ni++) { f32x4 z = {0.f,0.f,0.f,0.f}; acc[mi][ni] = z; }

  for (int k = 0; k < KT; ++k) {
    const int cur = k & 1;
    if (k + 1 < KT) {
      const int nxt = cur ^ 1;
      const size_t ko = (size_t)(k + 1) * BK;
      bf16_t* la = &As[nxt][0];
      bf16_t* lb_ = &Bs[nxt][0];
      async16(gA0 + ko, la + t * 8);
      async16(gA1 + ko, la + 2048 + t * 8);
      async16(gB0 + ko, lb_ + t * 8);
      async16(gB1 + ko, lb_ + 2048 + t * 8);
    }

    bf16x8 afr[4], bfr[4];
#pragma unroll
    for (int mi = 0; mi < 4; mi++)
      afr[mi] = *(const bf16x8*)(&As[cur][(wm + mi * 16 + l15) * BK + quad * 8]);
#pragma unroll
    for (int ni = 0; ni < 4; ni++)
      bfr[ni] = *(const bf16x8*)(&Bs[cur][(wn + ni * 16 + l15) * BK + quad * 8]);
#pragma unroll
    for (int mi = 0; mi < 4; mi++)
#pragma unroll
      for (int ni = 0; ni < 4; ni++)
        acc[mi][ni] = __builtin_amdgcn_mfma_f32_16x16x32_bf16(afr[mi], bfr[ni],
                                                              acc[mi][ni], 0, 0, 0);
    __syncthreads();
  }

  float b2n[4];
#pragma unroll
  for (int ni = 0; ni < 4; ni++) b2n[ni] = b2[n0 + wn + ni * 16 + l15];

#pragma unroll
  for (int mi = 0; mi < 4; mi++) {
#pragma unroll
    for (int r = 0; r < 4; r++) {
      int rloc = wm + mi * 16 + quad * 4 + r;
      int mrow = m0 + rloc;
      float a2v = a2[mrow < N_PATCH ? mrow : (N_PATCH - 1)];
      // C/D layout: col = lane&15, row = quad*4 + reg  [m89/m91]
      float best = a2v + b2n[0] - 2.0f * acc[mi][0][r];
#pragma unroll
      for (int ni = 1; ni < 4; ni++)
        best = fminf(best, a2v + b2n[ni] - 2.0f * acc[mi][ni][r]);
      best = fmaxf(best, 0.0f);
#pragma unroll
      for (int s = 1; s < 16; s <<= 1)
        best = fminf(best, __shfl_xor(best, s, 64));
      if (l15 == 0) atomicMin(&smin[rloc], __float_as_uint(best));
    }
  }
  __syncthreads();
  if (t < 128) part[(size_t)ntile * N_PATCH_PAD + m0 + t] = __uint_as_float(smin[t]);
}

// inline "pick": wave-level max over candidates
__device__ __forceinline__ void wave_pick(const Scal* sc, int cnt, int lane,
                                          int* srow, float* sstar, int* ms) {
  unsigned long long pk = 0ULL;
  int rowv = 0, msv = 0;
  if (lane < cnt) {
    unsigned long long cp = sc->cand_pack[lane];
    rowv = sc->cand[lane];
    msv = (int)(cp & 0xffffffffu);
    pk = (cp & 0xffffffff00000000ULL) | (unsigned)(0xffffffffu - (unsigned)rowv);
  }
  unsigned long long m = pk;
#pragma unroll
  for (int s = 1; s < 64; s <<= 1) {
    unsigned long long o = shfl_xor_u64(m, s);
    if (o > m) m = o;
  }
  unsigned long long mask = __ballot(pk == m && lane < cnt);
  int wl = (int)(__ffsll((long long)mask) - 1);
  *srow = __shfl(rowv, wl, 64);
  *ms   = __shfl(msv, wl, 64);
  *sstar = sqrtf(__uint_as_float((unsigned)(m >> 32)));
}

// ------------------------------------------------- tail (single dispatch, 64 blocks):
// P0 finalize -> bar -> P1 collect -> bar -> P2 tile-targeted fp32 refine -> bar ->
// P3 wdist (bf16, selection only) -> bar -> P4 (top3+s on block 0 || resize+blur 1..49)
__global__ __launch_bounds__(256, 2)
void tail_kernel(const float* __restrict__ part, float* __restrict__ min_val,
                 const float* __restrict__ patch, const float* __restrict__ lib,
                 const bf16_t* __restrict__ lb,
                 const float* __restrict__ meanp, const float* __restrict__ stdp,
                 Scal* __restrict__ sc, float* __restrict__ wdist2,
                 float* __restrict__ out0, float* __restrict__ outmap) {
  __shared__ union {
    unsigned long long sl[768];   // top3
    float rs[40 * 40];            // resize halo
  } sm;
  __shared__ float redbuf[4];
  __shared__ int s_cnt;

  const int t = threadIdx.x;
  const int b = blockIdx.x;
  const int wave = t >> 6, lane = t & 63;

  // ---- P0: finalize (blocks 0..12 cover 3136 rows; coalesced column reads) ----
  {
    int row = b * 256 + t;
    if (row < N_PATCH) {
      float m = FLT_MAX_;
#pragma unroll 8
      for (int nt = 0; nt < NTILES; nt++)
        m = fminf(m, part[(size_t)nt * N_PATCH_PAD + row]);
      float v = sqrtf(m);
      min_val[row] = v;
      unsigned long long mp = (((unsigned long long)__float_as_uint(v)) << 32) |
                              (unsigned)(0xffffffffu - (unsigned)row);  // ties -> smaller row
      atomicMax(&sc->approx_max_pack, mp);
    }
  }
  grid_bar(&sc->bar[0], TAILB);

  // ---- P1: collect candidates (block 0; margin 0.05 ~ 10 sigma of bf16 dist noise) ----
  if (b == 0) {
    float amax = __uint_as_float((unsigned)(atomicMax(&sc->approx_max_pack, 0ULL) >> 32));
    for (int i = t; i < N_PATCH; i += 256) {
      if (min_val[i] >= amax - 0.05f) {
        int p = atomicAdd(&sc->cand_count, 1);
        if (p < 64) sc->cand[p] = i;
      }
    }
  }
  grid_bar(&sc->bar[1], TAILB);

  if (t == 0) s_cnt = atomicAdd(&sc->cand_count, 0);
  __syncthreads();
  int cnt = s_cnt; if (cnt > 64) cnt = 64;

  // ---- P2: tile-targeted exact refine. Block b owns ntiles {2b, 2b+1}.
  // Only tiles whose bf16 partial min is within D2_MARGIN of the row's global
  // partial min get a 128-row fp32 rescan (true argmin provably inside margin).
  {
    float mu = meanp[0], sd = stdp[0];
    for (int c = 0; c < cnt; c++) {
      int row = sc->cand[c];
      // block-wide min over all 128 partials for this row
      float pv_ = (t < NTILES) ? part[(size_t)t * N_PATCH_PAD + row] : FLT_MAX_;
      pv_ = wave_reduce_min(pv_);
      if (lane == 0) redbuf[wave] = pv_;
      __syncthreads();
      float bmin = fminf(fminf(redbuf[0], redbuf[1]), fminf(redbuf[2], redbuf[3]));
      __syncthreads();

      float4 pv[3];
#pragma unroll
      for (int k = 0; k < 3; k++) {
        float4 v = ((const float4*)(patch + (size_t)row * DIM))[lane + 64 * k];
        v.x = (v.x - mu) / sd; v.y = (v.y - mu) / sd;
        v.z = (v.z - mu) / sd; v.w = (v.w - mu) / sd;
        pv[k] = v;
      }
#pragma unroll
      for (int tt = 0; tt < 2; tt++) {
        int nt = 2 * b + tt;
        float pmin = part[(size_t)nt * N_PATCH_PAD + row];   // uniform -> broadcast
        if (pmin <= bmin + D2_MARGIN) {
          unsigned long long best = ~0ULL;
          int jb = nt * 128 + wave * 32;
          for (int rr = 0; rr < 32; rr++) {
            int j = jb + rr;
            const float4* pl = (const float4*)(lib + (size_t)j * DIM);
            float acc = 0.f;
#pragma unroll
            for (int k = 0; k < 3; k++) {
              float4 l = pl[lane + 64 * k];
              float dx = pv[k].x - l.x, dy = pv[k].y - l.y;
              float dz = pv[k].z - l.z, dw = pv[k].w - l.w;
              acc += dx*dx + dy*dy + dz*dz + dw*dw;
            }
            acc = wave_reduce_sum(acc);
            unsigned long long pk = (((unsigned long long)__float_as_uint(acc)) << 32) | (unsigned)j;
            if (pk < best) best = pk;
          }
          if (lane == 0) atomicMin(&sc->cand_pack[c], best);
        }
      }
    }
  }
  grid_bar(&sc->bar[2], TAILB);

  // ---- P3: wdist on bf16 lb (selection only; exact d's recomputed in P4a) ----
  {
    int srow_, ms; float ss_;
    wave_pick(sc, cnt, lane, &srow_, &ss_, &ms);
    float pm[12];
    const ushort4* pms = (const ushort4*)(lb + (size_t)ms * DIM);
#pragma unroll
    for (int k = 0; k < 3; k++) {
      ushort4 u = pms[lane + 64 * k];
      pm[k*4+0] = bf16u_to_f(u.x); pm[k*4+1] = bf16u_to_f(u.y);
      pm[k*4+2] = bf16u_to_f(u.z); pm[k*4+3] = bf16u_to_f(u.w);
    }
    int jbase = b * 256 + wave * 64;
    for (int rr = 0; rr < 64; rr += 2) {
      int j0 = jbase + rr, j1 = j0 + 1;
      const ushort4* r0 = (const ushort4*)(lb + (size_t)j0 * DIM);
      const ushort4* r1 = (const ushort4*)(lb + (size_t)j1 * DIM);
      float a0 = 0.f, a1 = 0.f;
#pragma unroll
      for (int k = 0; k < 3; k++) {
        ushort4 u0 = r0[lane + 64 * k];
        ushort4 u1 = r1[lane + 64 * k];
        float d;
        d = bf16u_to_f(u0.x) - pm[k*4+0]; a0 += d * d;
        d = bf16u_to_f(u0.y) - pm[k*4+1]; a0 += d * d;
        d = bf16u_to_f(u0.z) - pm[k*4+2]; a0 += d * d;
        d = bf16u_to_f(u0.w) - pm[k*4+3]; a0 += d * d;
        d = bf16u_to_f(u1.x) - pm[k*4+0]; a1 += d * d;
        d = bf16u_to_f(u1.y) - pm[k*4+1]; a1 += d * d;
        d = bf16u_to_f(u1.z) - pm[k*4+2]; a1 += d * d;
        d = bf16u_to_f(u1.w) - pm[k*4+3]; a1 += d * d;
      }
      a0 = wave_reduce_sum(a0);
      a1 = wave_reduce_sum(a1);
      if (lane == 0) { wdist2[j0] = a0; wdist2[j1] = a1; }
    }
  }
  grid_bar(&sc->bar[3], TAILB);

  // ---- P4a: top3 (approx selection) + exact scalar s (block 0) ----
  if (b == 0) {
    unsigned long long b0 = ~0ULL, b1 = ~0ULL, b2 = ~0ULL;
    for (int j = t; j < N_LIB; j += 256) {
      unsigned long long pk = (((unsigned long long)__float_as_uint(wdist2[j])) << 32) | (unsigned)j;
      if (pk < b0)      { b2 = b1; b1 = b0; b0 = pk; }
      else if (pk < b1) { b2 = b1; b1 = pk; }
      else if (pk < b2) { b2 = pk; }
    }
    sm.sl[t * 3 + 0] = b0; sm.sl[t * 3 + 1] = b1; sm.sl[t * 3 + 2] = b2;
    __syncthreads();
    if (t >= 64) return;

    unsigned long long c0 = ~0ULL, c1 = ~0ULL, c2 = ~0ULL;
#pragma unroll
    for (int e = 0; e < 12; e++) {
      unsigned long long pk = sm.sl[t * 12 + e];
      if (pk < c0)      { c2 = c1; c1 = c0; c0 = pk; }
      else if (pk < c1) { c2 = c1; c1 = pk; }
      else if (pk < c2) { c2 = pk; }
    }
    unsigned long long res1 = 0, res2 = 0;
#pragma unroll
    for (int r = 0; r < 3; r++) {
      unsigned long long m = c0;
#pragma unroll
      for (int s = 1; s < 64; s <<= 1) {
        unsigned long long o = shfl_xor_u64(m, s);
        if (o < m) m = o;
      }
      if (r == 1) res1 = m;
      if (r == 2) res2 = m;
      if (c0 == m) { c0 = c1; c1 = c2; c2 = ~0ULL; }
    }
    int nA = (int)(res1 & 0xffffffffu);   // 2nd nearest
    int nB = (int)(res2 & 0xffffffffu);   // 3rd nearest

    int srow, ms2; float sstar;
    wave_pick(sc, cnt, t, &srow, &sstar, &ms2);

    float mu = meanp[0], sd = stdp[0];
    float accA = 0.f, accB = 0.f;
#pragma unroll
    for (int k = 0; k < 3; k++) {
      float4 p4 = ((const float4*)(patch + (size_t)srow * DIM))[t + 64 * k];
      float4 a4 = ((const float4*)(lib + (size_t)nA * DIM))[t + 64 * k];
      float4 b4 = ((const float4*)(lib + (size_t)nB * DIM))[t + 64 * k];
      float px = (p4.x - mu) / sd, py = (p4.y - mu) / sd;
      float pz = (p4.z - mu) / sd, pw = (p4.w - mu) / sd;
      float dax = px - a4.x, day = py - a4.y, daz = pz - a4.z, daw = pw - a4.w;
      float dbx = px - b4.x, dby = py - b4.y, dbz = pz - b4.z, dbw = pw - b4.w;
      accA += dax*dax + day*day + daz*daz + daw*daw;
      accB += dbx*dbx + dby*dby + dbz*dbz + dbw*dbw;
    }
    accA = wave_reduce_sum(accA);
    accB = wave_reduce_sum(accB);
    if (t == 0) {
      float dsq = sqrtf((float)DIM);
      float d1 = sqrtf(accA), d2v = sqrtf(accB);
      float w = 1.0f - expf(sstar / dsq) / (expf(d1 / dsq) + expf(d2v / dsq));
      out0[0] = w * sstar;
    }
    return;
  }

  // ---- P4b: fused bilinear 56->224 + 9x9 blur (blocks 1..49) ----
  if (b > 49) return;
  {
    int tile = b - 1;
    int bx = tile % 7, by = tile / 7;
    int ox0 = bx * 32, oy0 = by * 32;

    for (int i = t; i < 1600; i += 256) {
      int ly = i / 40, lx = i % 40;
      int gy = oy0 - 4 + ly; gy = gy < 0 ? 0 : (gy > 223 ? 223 : gy);
      int gx = ox0 - 4 + lx; gx = gx < 0 ? 0 : (gx > 223 ? 223 : gx);
      float sy = fminf(fmaxf(0.25f * gy - 0.375f, 0.0f), 55.0f);
      float sx = fminf(fmaxf(0.25f * gx - 0.375f, 0.0f), 55.0f);
      int y0 = (int)sy; if (y0 > 54) y0 = 54;
      int x0 = (int)sx; if (x0 > 54) x0 = 54;
      float fy = sy - y0, fx = sx - x0;
      float v00 = min_val[y0*FM + x0],     v01 = min_val[y0*FM + x0 + 1];
      float v10 = min_val[(y0+1)*FM + x0], v11 = min_val[(y0+1)*FM + x0 + 1];
      float a = v00 + fx * (v01 - v00);
      float bb = v10 + fx * (v11 - v10);
      sm.rs[i] = a + fy * (bb - a);
    }
    __syncthreads();

    float g[9]; float gs = 0.f;
#pragma unroll
    for (int i = 0; i < 9; i++) { float tt = (float)(i - 4); g[i] = expf(-(tt*tt)/32.0f); gs += g[i]; }
#pragma unroll
    for (int i = 0; i < 9; i++) g[i] /= gs;

    for (int p = t; p < 1024; p += 256) {
      int y = oy0 + p / 32, x = ox0 + (p & 31);
      float acc = 0.f;
#pragma unroll
      for (int dy = 0; dy < 9; dy++) {
        int yy = y + dy - 4;
        yy = yy < 0 ? -yy : (yy > IMGSZ - 1 ? 2*(IMGSZ-1) - yy : yy);
        int lyy = yy - (oy0 - 4);
        float ra = 0.f;
#pragma unroll
        for (int dx = 0; dx < 9; dx++) {
          int xx = x + dx - 4;
          xx = xx < 0 ? -xx : (xx > IMGSZ - 1 ? 2*(IMGSZ-1) - xx : xx);
          ra += g[dx] * sm.rs[lyy * 40 + (xx - (ox0 - 4))];
        }
        acc += g[dy] * ra;
      }
      outmap[y * IMGSZ + x] = acc;
    }
  }
}

// ================================================= host
extern "C" void kernel_launch(void* const* d_in, const int* in_sizes, int n_in,
                              void* d_out, int out_size, void* d_ws, size_t ws_size,
                              hipStream_t stream) {
  const float* patch = (const float*)d_in[0];
  const float* lib   = (const float*)d_in[1];
  const float* meanp = (const float*)d_in[2];
  const float* stdp  = (const float*)d_in[3];
  float* out = (float*)d_out;

  char* ws = (char*)d_ws;
  size_t off = 0;
  auto alloc = [&](size_t bytes) -> void* {
    void* p = ws + off;
    off = (off + bytes + 255) & ~(size_t)255;
    return p;
  };
  bf16_t* pb      = (bf16_t*)alloc((size_t)N_PATCH * DIM * sizeof(bf16_t));
  bf16_t* lb      = (bf16_t*)alloc((size_t)N_LIB * DIM * sizeof(bf16_t));
  float* a2       = (float*)alloc(N_PATCH * sizeof(float));
  float* b2       = (float*)alloc(N_LIB * sizeof(float));
  float* part     = (float*)alloc((size_t)N_PATCH_PAD * NTILES * sizeof(float));
  float* min_val  = (float*)alloc(N_PATCH * sizeof(float));
  float* wdist2   = (float*)alloc(N_LIB * sizeof(float));
  Scal*  sc       = (Scal*)alloc(sizeof(Scal));

  prep_kernel<<<N_PATCH / 4 + N_LIB / 4, 256, 0, stream>>>(patch, lib, meanp, stdp,
                                                           pb, lb, a2, b2, sc);
  gemm_min_kernel<<<MT * NTILES, 256, 0, stream>>>(pb, lb, a2, b2, part);
  tail_kernel<<<TAILB, 256, 0, stream>>>(part, min_val, patch, lib, lb, meanp, stdp,
                                         sc, wdist2, out, out + 1);
}